// Round 2
// baseline (974.722 us; speedup 1.0000x reference)
//
#include <hip/hip_runtime.h>
#include <math.h>

// N=1M nodes, E=32M edges. Counting-sort edges by dst-bucket; aggregation
// uses LDS atomics (global atomics cap ~20.7 G/s per R3).
// R6 lesson: k_agg1 pinned at 183us regardless of occupancy (44->78%) with
// VALU 2.7%, HBM 8% -> saturated random-gather request throughput (~175 G/s,
// ~11 TB/s of L3 line traffic). R7 (this round): ELIMINATE the pass-1 gather:
// k_permute gathers m[src] (overlapped with its stream/LDS work) and emits a
// parallel f32 mval stream; k_agg1mv is then a pure stream + LDS atomics.
// f32 (not f16) mvals: classification sign margins too tight for f16.
// CHUNK 8192->4096 keeps permute at 40KB LDS -> 4 blocks/CU.
//
// record = (src << 12) | (dst & 4095)   [src < 2^20]
// ws: m (4MB) | gcur (1KB) | y/pk alias (4MB) | cls2 (256KB)
//     | gsorted (NB*CAP*4 ~132MB) | gmval (NB*CAP*4 ~132MB, plan-A only)

#define EPS 1e-15f
#define CHUNK 4096
#define PTHREADS 512
#define NBINS 256
#define BNODES 4096
#define SPLITS 4

typedef int          vint4  __attribute__((ext_vector_type(4)));
typedef unsigned int vuint4 __attribute__((ext_vector_type(4)));
typedef float        vflt4  __attribute__((ext_vector_type(4)));

// ===================== sort path =====================

__global__ __launch_bounds__(256)
void k_prep2(const float2* __restrict__ x, const float* __restrict__ W,
             float* __restrict__ m, float* __restrict__ y,
             unsigned int* __restrict__ gcur,
             int N, int NB, unsigned int CAP) {
    int i = blockIdx.x * 256 + threadIdx.x;
    if (i < N) {
        float2 v = x[i];
        float inv = 1.0f / (sqrtf(v.x * v.x + v.y * v.y) + EPS);
        m[i] = (v.x * inv) * W[0] + (v.y * inv) * W[2];
        y[i] = 0.0f;
    }
    if (i < NB) gcur[i] = (unsigned)i * CAP;
}

// WM=true: also gather m[src] and emit gmval parallel to gsorted.
template<bool WM>
__global__ __launch_bounds__(PTHREADS)
void k_permute(const int* __restrict__ src, const int* __restrict__ dst,
               const float* __restrict__ m,
               unsigned int* __restrict__ gsorted, float* __restrict__ gmval,
               unsigned int* __restrict__ gcur, int E) {
    __shared__ unsigned int  sh_sorted[CHUNK];   // 16 KB staged records
    __shared__ float         sh_mval[CHUNK];     // 16 KB staged m values
    __shared__ unsigned char sh_bin[CHUNK];      //  4 KB bin of each slot
    __shared__ unsigned int  sh_hist[NBINS];     //  1 KB counts -> cursor
    __shared__ unsigned int  sh_loff[NBINS];     //  1 KB local bin starts
    __shared__ unsigned int  sh_delta[NBINS];    //  1 KB global base - local start
    __shared__ unsigned int  sh_scan[NBINS];     //  1 KB scan scratch
    const int tid = threadIdx.x;
    const long long e0 = (long long)blockIdx.x * CHUNK;
    const int n = (int)min((long long)CHUNK, (long long)E - e0);
    const int nv4 = (n >> 2) << 2;

    if (tid < NBINS) sh_hist[tid] = 0u;
    __syncthreads();

    // phase 1: bucket histogram of dst (cached loads; phase-3 re-read hits L2)
    #pragma unroll
    for (int k = 0; k < CHUNK / (PTHREADS * 4); ++k) {
        int o = (k * PTHREADS + tid) * 4;
        if (o < nv4) {
            vint4 d = *(const vint4*)(dst + e0 + o);
            atomicAdd(&sh_hist[((unsigned)d.x) >> 12], 1u);
            atomicAdd(&sh_hist[((unsigned)d.y) >> 12], 1u);
            atomicAdd(&sh_hist[((unsigned)d.z) >> 12], 1u);
            atomicAdd(&sh_hist[((unsigned)d.w) >> 12], 1u);
        }
    }
    for (int j = nv4 + tid; j < n; j += PTHREADS)
        atomicAdd(&sh_hist[((unsigned)dst[e0 + j]) >> 12], 1u);
    __syncthreads();

    // phase 2: scan 256 bins + global range reservation (1 atomic per nonempty bin)
    if (tid < NBINS) sh_scan[tid] = sh_hist[tid];
    __syncthreads();
    for (int off = 1; off < NBINS; off <<= 1) {
        unsigned v = 0;
        if (tid < NBINS && tid >= off) v = sh_scan[tid - off];
        __syncthreads();
        if (tid < NBINS) sh_scan[tid] += v;
        __syncthreads();
    }
    if (tid < NBINS) {
        unsigned h = sh_hist[tid];
        unsigned lo = sh_scan[tid] - h;     // exclusive prefix
        sh_loff[tid] = lo;
        if (h) sh_delta[tid] = atomicAdd(&gcur[tid], h) - lo;
    }
    __syncthreads();
    if (tid < NBINS) sh_hist[tid] = sh_loff[tid];   // running cursor
    __syncthreads();

    // phase 3: re-read src+dst (+gather m[src] if WM), scatter into LDS in bin order
    #pragma unroll
    for (int k = 0; k < CHUNK / (PTHREADS * 4); ++k) {
        int o = (k * PTHREADS + tid) * 4;
        if (o < nv4) {
            vint4 s = __builtin_nontemporal_load((const vint4*)(src + e0 + o));
            vint4 d = *(const vint4*)(dst + e0 + o);
            float mv0 = 0.f, mv1 = 0.f, mv2 = 0.f, mv3 = 0.f;
            if constexpr (WM) {
                mv0 = m[s.x]; mv1 = m[s.y]; mv2 = m[s.z]; mv3 = m[s.w];
            }
            unsigned b, p;
            b = ((unsigned)d.x) >> 12; p = atomicAdd(&sh_hist[b], 1u);
            sh_sorted[p] = ((unsigned)s.x << 12) | ((unsigned)d.x & 4095u); sh_bin[p] = (unsigned char)b;
            if constexpr (WM) sh_mval[p] = mv0;
            b = ((unsigned)d.y) >> 12; p = atomicAdd(&sh_hist[b], 1u);
            sh_sorted[p] = ((unsigned)s.y << 12) | ((unsigned)d.y & 4095u); sh_bin[p] = (unsigned char)b;
            if constexpr (WM) sh_mval[p] = mv1;
            b = ((unsigned)d.z) >> 12; p = atomicAdd(&sh_hist[b], 1u);
            sh_sorted[p] = ((unsigned)s.z << 12) | ((unsigned)d.z & 4095u); sh_bin[p] = (unsigned char)b;
            if constexpr (WM) sh_mval[p] = mv2;
            b = ((unsigned)d.w) >> 12; p = atomicAdd(&sh_hist[b], 1u);
            sh_sorted[p] = ((unsigned)s.w << 12) | ((unsigned)d.w & 4095u); sh_bin[p] = (unsigned char)b;
            if constexpr (WM) sh_mval[p] = mv3;
        }
    }
    for (int j = nv4 + tid; j < n; j += PTHREADS) {
        unsigned dv = (unsigned)dst[e0 + j], sv = (unsigned)src[e0 + j];
        float mv = 0.f;
        if constexpr (WM) mv = m[sv];
        unsigned b = dv >> 12;
        unsigned p = atomicAdd(&sh_hist[b], 1u);
        sh_sorted[p] = (sv << 12) | (dv & 4095u);
        sh_bin[p] = (unsigned char)b;
        if constexpr (WM) sh_mval[p] = mv;
    }
    __syncthreads();

    // phase 4: coalesced copy-out via direct bin lookup
    for (int t = tid; t < n; t += PTHREADS) {
        unsigned o = sh_delta[sh_bin[t]] + (unsigned)t;
        gsorted[o] = sh_sorted[t];
        if constexpr (WM) gmval[o] = sh_mval[t];
    }
}

// pass 1 aggregate (plan A): pure stream of (record, mval) pairs -> LDS
// atomics. Zero random gathers. Bucket b handled by SPLITS blocks.
__global__ __launch_bounds__(1024)
void k_agg1mv(const unsigned int* __restrict__ gsorted, const float* __restrict__ gmval,
              const unsigned int* __restrict__ gcur, float* __restrict__ y,
              int N, unsigned int CAP, int NB) {
    __shared__ float yloc[BNODES];   // 16 KB
    const int tid = threadIdx.x;
    const int b = blockIdx.x % NB;
    const int split = blockIdx.x / NB;
    for (int j = tid; j < BNODES; j += 1024) yloc[j] = 0.0f;
    __syncthreads();
    const unsigned base = (unsigned)b * CAP;
    const unsigned cnt = gcur[b] - base;
    const unsigned nv = cnt >> 2;
    const vuint4* pv = (const vuint4*)(gsorted + base);
    const vflt4*  pm = (const vflt4*)(gmval + base);
    const unsigned stride = SPLITS * 1024u;
    unsigned k = (unsigned)split * 1024u + (unsigned)tid;
    for (; k + stride < nv; k += 2u * stride) {
        vuint4 r0 = __builtin_nontemporal_load(pv + k);
        vflt4  w0 = __builtin_nontemporal_load(pm + k);
        vuint4 r1 = __builtin_nontemporal_load(pv + k + stride);
        vflt4  w1 = __builtin_nontemporal_load(pm + k + stride);
        atomicAdd(&yloc[r0.x & 4095u], w0.x);
        atomicAdd(&yloc[r0.y & 4095u], w0.y);
        atomicAdd(&yloc[r0.z & 4095u], w0.z);
        atomicAdd(&yloc[r0.w & 4095u], w0.w);
        atomicAdd(&yloc[r1.x & 4095u], w1.x);
        atomicAdd(&yloc[r1.y & 4095u], w1.y);
        atomicAdd(&yloc[r1.z & 4095u], w1.z);
        atomicAdd(&yloc[r1.w & 4095u], w1.w);
    }
    for (; k < nv; k += stride) {
        vuint4 r = __builtin_nontemporal_load(pv + k);
        vflt4  w = __builtin_nontemporal_load(pm + k);
        atomicAdd(&yloc[r.x & 4095u], w.x);
        atomicAdd(&yloc[r.y & 4095u], w.y);
        atomicAdd(&yloc[r.z & 4095u], w.z);
        atomicAdd(&yloc[r.w & 4095u], w.w);
    }
    if (split == 0) {
        for (unsigned i = (nv << 2) + tid; i < cnt; i += 1024) {
            unsigned p = gsorted[base + i];
            atomicAdd(&yloc[p & 4095u], gmval[base + i]);
        }
    }
    __syncthreads();
    const int nbase = b * BNODES;
    for (int j = tid; j < BNODES; j += 1024) {
        float v = yloc[j];
        int node = nbase + j;
        if (node < N && v != 0.0f) unsafeAtomicAdd(&y[node], v);
    }
}

// pass 1 aggregate (contingency, R6): gathers m[src] per record.
__global__ __launch_bounds__(1024)
void k_agg1g(const unsigned int* __restrict__ gsorted, const unsigned int* __restrict__ gcur,
             const float* __restrict__ m, float* __restrict__ y,
             int N, unsigned int CAP, int NB) {
    __shared__ float yloc[BNODES];   // 16 KB
    const int tid = threadIdx.x;
    const int b = blockIdx.x % NB;
    const int split = blockIdx.x / NB;
    for (int j = tid; j < BNODES; j += 1024) yloc[j] = 0.0f;
    __syncthreads();
    const unsigned base = (unsigned)b * CAP;
    const unsigned cnt = gcur[b] - base;
    const unsigned nv = cnt >> 2;
    const vuint4* pv = (const vuint4*)(gsorted + base);
    const unsigned stride = SPLITS * 1024u;
    unsigned k = (unsigned)split * 1024u + (unsigned)tid;
    for (; k + stride < nv; k += 2u * stride) {
        vuint4 p0 = __builtin_nontemporal_load(pv + k);
        vuint4 p1 = __builtin_nontemporal_load(pv + k + stride);
        float m0 = m[p0.x >> 12], m1 = m[p0.y >> 12];
        float m2 = m[p0.z >> 12], m3 = m[p0.w >> 12];
        float m4 = m[p1.x >> 12], m5 = m[p1.y >> 12];
        float m6 = m[p1.z >> 12], m7 = m[p1.w >> 12];
        atomicAdd(&yloc[p0.x & 4095u], m0);
        atomicAdd(&yloc[p0.y & 4095u], m1);
        atomicAdd(&yloc[p0.z & 4095u], m2);
        atomicAdd(&yloc[p0.w & 4095u], m3);
        atomicAdd(&yloc[p1.x & 4095u], m4);
        atomicAdd(&yloc[p1.y & 4095u], m5);
        atomicAdd(&yloc[p1.z & 4095u], m6);
        atomicAdd(&yloc[p1.w & 4095u], m7);
    }
    for (; k < nv; k += stride) {
        vuint4 p = __builtin_nontemporal_load(pv + k);
        atomicAdd(&yloc[p.x & 4095u], m[p.x >> 12]);
        atomicAdd(&yloc[p.y & 4095u], m[p.y >> 12]);
        atomicAdd(&yloc[p.z & 4095u], m[p.z >> 12]);
        atomicAdd(&yloc[p.w & 4095u], m[p.w >> 12]);
    }
    if (split == 0) {
        for (unsigned i = (nv << 2) + tid; i < cnt; i += 1024) {
            unsigned p = gsorted[base + i];
            atomicAdd(&yloc[p & 4095u], m[p >> 12]);
        }
    }
    __syncthreads();
    const int nbase = b * BNODES;
    for (int j = tid; j < BNODES; j += 1024) {
        float v = yloc[j];
        int node = nbase + j;
        if (node < N && v != 0.0f) unsafeAtomicAdd(&y[node], v);
    }
}

// classify: pack 16 node classes per u32 word (2 bits each), zero pk.
// pk aliases y (read y first, then overwrite with 0) — each thread owns
// its 16 slots exclusively, so the alias is safe.
__global__ __launch_bounds__(256)
void k_classify2(const float* __restrict__ y, unsigned int* __restrict__ cls2,
                 unsigned int* __restrict__ pk, int N) {
    int i = blockIdx.x * 256 + threadIdx.x;   // word index
    int nw = (N + 15) >> 4;
    if (i >= nw) return;
    int n0 = i << 4;
    unsigned w = 0u;
    if (n0 + 16 <= N) {
        const float4* yv = (const float4*)(y + n0);
        float4 v0 = yv[0], v1 = yv[1], v2 = yv[2], v3 = yv[3];
        float vv[16] = {v0.x, v0.y, v0.z, v0.w, v1.x, v1.y, v1.z, v1.w,
                        v2.x, v2.y, v2.z, v2.w, v3.x, v3.y, v3.z, v3.w};
        #pragma unroll
        for (int j = 0; j < 16; ++j) {
            unsigned c = (vv[j] > 0.0f) ? 1u : ((vv[j] < 0.0f) ? 2u : 0u);
            w |= c << (j * 2);
        }
        int4 z = {0, 0, 0, 0};
        int4* pz = (int4*)(pk + n0);
        pz[0] = z; pz[1] = z; pz[2] = z; pz[3] = z;
    } else {
        for (int j = 0; n0 + j < N; ++j) {
            float v = y[n0 + j];
            unsigned c = (v > 0.0f) ? 1u : ((v < 0.0f) ? 2u : 0u);
            w |= c << (j * 2);
            pk[n0 + j] = 0u;
        }
    }
    cls2[i] = w;
}

// pass 2 aggregate: packed class counts per dst, split like pass 1.
// class word gather hits a 256 KB L2-resident array.
__global__ __launch_bounds__(1024)
void k_agg2s(const unsigned int* __restrict__ gsorted, const unsigned int* __restrict__ gcur,
             const unsigned int* __restrict__ cls2, unsigned int* __restrict__ pk,
             int N, unsigned int CAP, int NB) {
    __shared__ unsigned int pkloc[BNODES];   // 16 KB
    const int tid = threadIdx.x;
    const int b = blockIdx.x % NB;
    const int split = blockIdx.x / NB;
    for (int j = tid; j < BNODES; j += 1024) pkloc[j] = 0u;
    __syncthreads();
    const unsigned base = (unsigned)b * CAP;
    const unsigned cnt = gcur[b] - base;
    const unsigned nv = cnt >> 2;
    const vuint4* pv = (const vuint4*)(gsorted + base);
    auto dec = [&](unsigned s) -> unsigned int {
        unsigned wd = cls2[s >> 4];
        unsigned cl = (wd >> ((s & 15u) << 1)) & 3u;
        // cl: 0 -> 0, 1 -> 1<<16, 2 -> 1
        return ((cl & 1u) << 16) | (cl >> 1);
    };
    const unsigned stride = SPLITS * 1024u;
    unsigned k = (unsigned)split * 1024u + (unsigned)tid;
    for (; k + stride < nv; k += 2u * stride) {
        vuint4 p0 = __builtin_nontemporal_load(pv + k);
        vuint4 p1 = __builtin_nontemporal_load(pv + k + stride);
        unsigned d0 = dec(p0.x >> 12), d1 = dec(p0.y >> 12);
        unsigned d2 = dec(p0.z >> 12), d3 = dec(p0.w >> 12);
        unsigned d4 = dec(p1.x >> 12), d5 = dec(p1.y >> 12);
        unsigned d6 = dec(p1.z >> 12), d7 = dec(p1.w >> 12);
        atomicAdd(&pkloc[p0.x & 4095u], d0);
        atomicAdd(&pkloc[p0.y & 4095u], d1);
        atomicAdd(&pkloc[p0.z & 4095u], d2);
        atomicAdd(&pkloc[p0.w & 4095u], d3);
        atomicAdd(&pkloc[p1.x & 4095u], d4);
        atomicAdd(&pkloc[p1.y & 4095u], d5);
        atomicAdd(&pkloc[p1.z & 4095u], d6);
        atomicAdd(&pkloc[p1.w & 4095u], d7);
    }
    for (; k < nv; k += stride) {
        vuint4 p = __builtin_nontemporal_load(pv + k);
        unsigned d0 = dec(p.x >> 12), d1 = dec(p.y >> 12);
        unsigned d2 = dec(p.z >> 12), d3 = dec(p.w >> 12);
        atomicAdd(&pkloc[p.x & 4095u], d0);
        atomicAdd(&pkloc[p.y & 4095u], d1);
        atomicAdd(&pkloc[p.z & 4095u], d2);
        atomicAdd(&pkloc[p.w & 4095u], d3);
    }
    if (split == 0) {
        for (unsigned i = (nv << 2) + tid; i < cnt; i += 1024) {
            unsigned p = gsorted[base + i];
            atomicAdd(&pkloc[p & 4095u], dec(p >> 12));
        }
    }
    __syncthreads();
    const int nbase = b * BNODES;
    for (int j = tid; j < BNODES; j += 1024) {
        unsigned v = pkloc[j];
        int node = nbase + j;
        if (node < N && v) atomicAdd(&pk[node], v);
    }
}

// ===================== fallback path (R3, atomic-based) =====================

__global__ __launch_bounds__(256)
void k_prep(const float2* __restrict__ x, const float* __restrict__ W,
            float* __restrict__ m, float* __restrict__ y,
            unsigned int* __restrict__ pk, int N) {
    int i = blockIdx.x * blockDim.x + threadIdx.x;
    if (i < N) {
        float2 v = x[i];
        float inv = 1.0f / (sqrtf(v.x * v.x + v.y * v.y) + EPS);
        m[i]  = (v.x * inv) * W[0] + (v.y * inv) * W[2];
        y[i]  = 0.0f;
        pk[i] = 0u;
    }
}

__global__ __launch_bounds__(256)
void k_scatter1(const int* __restrict__ src, const int* __restrict__ dst,
                const float* __restrict__ m, float* __restrict__ y, int E) {
    int t = blockIdx.x * blockDim.x + threadIdx.x;
    int i = t * 8;
    if (i + 8 <= E) {
        vint4 s0 = __builtin_nontemporal_load((const vint4*)(src + i));
        vint4 s1 = __builtin_nontemporal_load((const vint4*)(src + i + 4));
        vint4 d0 = __builtin_nontemporal_load((const vint4*)(dst + i));
        vint4 d1 = __builtin_nontemporal_load((const vint4*)(dst + i + 4));
        unsafeAtomicAdd(&y[d0.x], m[s0.x]);
        unsafeAtomicAdd(&y[d0.y], m[s0.y]);
        unsafeAtomicAdd(&y[d0.z], m[s0.z]);
        unsafeAtomicAdd(&y[d0.w], m[s0.w]);
        unsafeAtomicAdd(&y[d1.x], m[s1.x]);
        unsafeAtomicAdd(&y[d1.y], m[s1.y]);
        unsafeAtomicAdd(&y[d1.z], m[s1.z]);
        unsafeAtomicAdd(&y[d1.w], m[s1.w]);
    } else if (i < E) {
        for (int j = i; j < E; ++j)
            unsafeAtomicAdd(&y[dst[j]], m[src[j]]);
    }
}

__global__ __launch_bounds__(256)
void k_classify(const float* __restrict__ y, unsigned char* __restrict__ cls, int N) {
    int i = blockIdx.x * blockDim.x + threadIdx.x;
    if (i < N) {
        float v = y[i];
        cls[i] = (v > 0.0f) ? 1 : ((v < 0.0f) ? 2 : 0);
    }
}

__global__ __launch_bounds__(256)
void k_scatter2(const int* __restrict__ src, const int* __restrict__ dst,
                const unsigned char* __restrict__ cls, unsigned int* __restrict__ pk,
                int E) {
    int t = blockIdx.x * blockDim.x + threadIdx.x;
    int i = t * 8;
    auto dec = [](unsigned char c) -> unsigned int {
        return (c == 1) ? 65536u : ((c == 2) ? 1u : 0u);
    };
    if (i + 8 <= E) {
        vint4 s0 = __builtin_nontemporal_load((const vint4*)(src + i));
        vint4 s1 = __builtin_nontemporal_load((const vint4*)(src + i + 4));
        vint4 d0 = __builtin_nontemporal_load((const vint4*)(dst + i));
        vint4 d1 = __builtin_nontemporal_load((const vint4*)(dst + i + 4));
        atomicAdd(&pk[d0.x], dec(cls[s0.x]));
        atomicAdd(&pk[d0.y], dec(cls[s0.y]));
        atomicAdd(&pk[d0.z], dec(cls[s0.z]));
        atomicAdd(&pk[d0.w], dec(cls[s0.w]));
        atomicAdd(&pk[d1.x], dec(cls[s1.x]));
        atomicAdd(&pk[d1.y], dec(cls[s1.y]));
        atomicAdd(&pk[d1.z], dec(cls[s1.z]));
        atomicAdd(&pk[d1.w], dec(cls[s1.w]));
    } else if (i < E) {
        for (int j = i; j < E; ++j)
            atomicAdd(&pk[dst[j]], dec(cls[src[j]]));
    }
}

__global__ __launch_bounds__(256)
void k_final(const unsigned int* __restrict__ pk, const float* __restrict__ W,
             const float* __restrict__ fw, float* __restrict__ out, int N) {
    int i = blockIdx.x * blockDim.x + threadIdx.x;
    if (i < N) {
        unsigned p = pk[i];
        float c0 = (float)(p >> 16);
        float c1 = (float)(p & 0xFFFFu);
        float x0 = fmaxf(c0 * W[0] + c1 * W[2], 0.0f);
        float x1 = fmaxf(c0 * W[1] + c1 * W[3], 0.0f);
        float z = x0 * fw[0] + x1 * fw[1];
        out[i] = 1.0f / (1.0f + expf(-z));
    }
}

// ===================== launch =====================

extern "C" void kernel_launch(void* const* d_in, const int* in_sizes, int n_in,
                              void* d_out, int out_size, void* d_ws, size_t ws_size,
                              hipStream_t stream) {
    const float* x  = (const float*)d_in[0];
    const int*   ei = (const int*)d_in[1];
    const float* W  = (const float*)d_in[2];
    const float* fw = (const float*)d_in[3];
    float*       out = (float*)d_out;

    const int N = in_sizes[0] / 2;
    const int E = in_sizes[1] / 2;
    const int* src = ei;
    const int* dst = ei + E;

    const int B  = 256;
    const int gN = (N + B - 1) / B;

    // sort-path sizing: 256 bins of 4096 nodes
    const int NB = (N + BNODES - 1) / BNODES;
    double mean = (double)E / ((double)N / (double)BNODES);
    unsigned CAP = (unsigned)(mean + 8.0 * sqrt(mean) + 1024.0);
    CAP = (CAP + 1023u) & ~1023u;

    const int NW = (N + 15) >> 4;   // packed class words

    char* p = (char*)d_ws;
    float*         m_s   = (float*)p;          p += (((size_t)N * 4 + 255) & ~255ULL);
    unsigned int*  gcur  = (unsigned int*)p;   p += (((size_t)NB * 4 + 255) & ~255ULL);
    float*         y_s   = (float*)p;          p += (((size_t)N * 4 + 255) & ~255ULL);
    unsigned int*  cls2  = (unsigned int*)p;   p += (((size_t)NW * 4 + 255) & ~255ULL);
    unsigned int*  gsorted = (unsigned int*)p;
    size_t sorted_bytes = (size_t)NB * CAP * 4ULL;
    float*         gmval = (float*)(p + ((sorted_bytes + 255) & ~255ULL));
    size_t fixed = (size_t)(p - (char*)d_ws);
    size_t need_g  = fixed + sorted_bytes;
    size_t need_mv = fixed + ((sorted_bytes + 255) & ~255ULL) + sorted_bytes;

    if (ws_size >= need_g && N <= (1 << 20) && NB <= NBINS) {
        const bool with_m = (ws_size >= need_mv);
        const int gP = (E + CHUNK - 1) / CHUNK;
        unsigned int* pk_s = (unsigned int*)y_s;   // pk aliases y (see k_classify2)
        k_prep2<<<gN, B, 0, stream>>>((const float2*)x, W, m_s, y_s, gcur, N, NB, CAP);
        if (with_m) {
            // plan A: m values ride with the sorted stream; agg1 has no gathers
            k_permute<true><<<gP, PTHREADS, 0, stream>>>(src, dst, m_s, gsorted, gmval, gcur, E);
            k_agg1mv<<<NB * SPLITS, 1024, 0, stream>>>(gsorted, gmval, gcur, y_s, N, CAP, NB);
        } else {
            // contingency (R6): gather-based agg1
            k_permute<false><<<gP, PTHREADS, 0, stream>>>(src, dst, m_s, gsorted, gmval, gcur, E);
            k_agg1g<<<NB * SPLITS, 1024, 0, stream>>>(gsorted, gcur, m_s, y_s, N, CAP, NB);
        }
        k_classify2<<<(NW + B - 1) / B, B, 0, stream>>>(y_s, cls2, pk_s, N);
        k_agg2s<<<NB * SPLITS, 1024, 0, stream>>>(gsorted, gcur, cls2, pk_s, N, CAP, NB);
        k_final<<<gN, B, 0, stream>>>(pk_s, W, fw, out, N);
    } else {
        // fallback: R3 atomic path
        char* q = (char*)d_ws;
        unsigned char* cls = (unsigned char*)q;  q += (((size_t)N + 255) & ~255ULL);
        float*         m   = (float*)q;          q += (((size_t)N * 4 + 255) & ~255ULL);
        float*         y   = (float*)q;          q += (((size_t)N * 4 + 255) & ~255ULL);
        unsigned int*  pk  = (unsigned int*)q;
        const int gE = (E / 8 + B - 1) / B + 1;
        k_prep<<<gN, B, 0, stream>>>((const float2*)x, W, m, y, pk, N);
        k_scatter1<<<gE, B, 0, stream>>>(src, dst, m, y, E);
        k_classify<<<gN, B, 0, stream>>>(y, cls, N);
        k_scatter2<<<gE, B, 0, stream>>>(src, dst, cls, pk, E);
        k_final<<<gN, B, 0, stream>>>(pk, W, fw, out, N);
    }
}

// Round 3
// 919.874 us; speedup vs baseline: 1.0596x; 1.0596x over previous
//
#include <hip/hip_runtime.h>
#include <math.h>

// N=1M nodes, E=32M edges. R5-R7 lesson: both aggregation passes were pinned
// at 183us = 32M per-lane random gather requests at ~175 G req/s, invariant
// to occupancy (44->78%), table size (4MB m vs 256KB cls2), and FETCH bytes.
// R7 (move gather into permute) regressed: gather thrashed permute's L2
// streams (FETCH 705MB) + 256MB mval stream. REVERTED.
// R8 (this round): kill the random requests entirely via a second MSB-radix
// pass WITHIN each dst-bucket keyed on src-bucket (rec>>24). Then both agg
// passes stage the 16KB m-tile / 1KB cls-tile in LDS and every edge is an
// LDS read + LDS atomicAdd -> requests become sequential line-granular tile
// loads (7.7M line reqs vs 32M scalar reqs).
//
// record = (src << 12) | (dst & 4095)   [src < 2^20, src-bucket = rec>>24]
// ws: m (4MB) | gcur (1KB) | y/pk alias (4MB) | cls2 (256KB)
//     | cnt2/gstart2/gcur2 (3x256KB) | gsorted (~132MB) | gsorted2 (~132MB)

#define EPS 1e-15f
#define CHUNK 8192      // permute1 edges/block
#define P2CHUNK 8192    // permute2 records/block
#define H2CHUNK 32768   // hist2 records/block
#define PTHREADS 512
#define NBINS 256
#define BNODES 4096
#define SPLITS 4        // agg blocks per bucket (each owns 64 src-buckets)

typedef int          vint4  __attribute__((ext_vector_type(4)));
typedef unsigned int vuint4 __attribute__((ext_vector_type(4)));

// ===================== sort path =====================

__global__ __launch_bounds__(256)
void k_prep2(const float2* __restrict__ x, const float* __restrict__ W,
             float* __restrict__ m, float* __restrict__ y,
             unsigned int* __restrict__ gcur, unsigned int* __restrict__ cnt2,
             int N, int NB, unsigned int CAP) {
    int i = blockIdx.x * 256 + threadIdx.x;
    if (i < N) {
        float2 v = x[i];
        float inv = 1.0f / (sqrtf(v.x * v.x + v.y * v.y) + EPS);
        m[i] = (v.x * inv) * W[0] + (v.y * inv) * W[2];
        y[i] = 0.0f;
    }
    if (i < NB) gcur[i] = (unsigned)i * CAP;
    if (cnt2 && i < NBINS * NBINS) cnt2[i] = 0u;
}

// pass 1 of radix: counting sort by dst-bucket (R6-proven form, CHUNK 8192)
__global__ __launch_bounds__(PTHREADS)
void k_permute(const int* __restrict__ src, const int* __restrict__ dst,
               unsigned int* __restrict__ gsorted, unsigned int* __restrict__ gcur,
               int E) {
    __shared__ unsigned int  sh_sorted[CHUNK];   // 32 KB staged records
    __shared__ unsigned char sh_bin[CHUNK];      //  8 KB bin of each slot
    __shared__ unsigned int  sh_hist[NBINS];     //  1 KB counts -> cursor
    __shared__ unsigned int  sh_loff[NBINS];     //  1 KB local bin starts
    __shared__ unsigned int  sh_delta[NBINS];    //  1 KB global base - local start
    __shared__ unsigned int  sh_scan[NBINS];     //  1 KB scan scratch
    const int tid = threadIdx.x;
    const long long e0 = (long long)blockIdx.x * CHUNK;
    const int n = (int)min((long long)CHUNK, (long long)E - e0);
    const int nv4 = (n >> 2) << 2;

    if (tid < NBINS) sh_hist[tid] = 0u;
    __syncthreads();

    // phase 1: bucket histogram of dst (cached loads; phase-3 re-read hits L2)
    #pragma unroll
    for (int k = 0; k < CHUNK / (PTHREADS * 4); ++k) {
        int o = (k * PTHREADS + tid) * 4;
        if (o < nv4) {
            vint4 d = *(const vint4*)(dst + e0 + o);
            atomicAdd(&sh_hist[((unsigned)d.x) >> 12], 1u);
            atomicAdd(&sh_hist[((unsigned)d.y) >> 12], 1u);
            atomicAdd(&sh_hist[((unsigned)d.z) >> 12], 1u);
            atomicAdd(&sh_hist[((unsigned)d.w) >> 12], 1u);
        }
    }
    for (int j = nv4 + tid; j < n; j += PTHREADS)
        atomicAdd(&sh_hist[((unsigned)dst[e0 + j]) >> 12], 1u);
    __syncthreads();

    // phase 2: scan 256 bins + global range reservation
    if (tid < NBINS) sh_scan[tid] = sh_hist[tid];
    __syncthreads();
    for (int off = 1; off < NBINS; off <<= 1) {
        unsigned v = 0;
        if (tid < NBINS && tid >= off) v = sh_scan[tid - off];
        __syncthreads();
        if (tid < NBINS) sh_scan[tid] += v;
        __syncthreads();
    }
    if (tid < NBINS) {
        unsigned h = sh_hist[tid];
        unsigned lo = sh_scan[tid] - h;     // exclusive prefix
        sh_loff[tid] = lo;
        if (h) sh_delta[tid] = atomicAdd(&gcur[tid], h) - lo;
    }
    __syncthreads();
    if (tid < NBINS) sh_hist[tid] = sh_loff[tid];   // running cursor
    __syncthreads();

    // phase 3: re-read src+dst, scatter packed records into LDS in bin order
    #pragma unroll
    for (int k = 0; k < CHUNK / (PTHREADS * 4); ++k) {
        int o = (k * PTHREADS + tid) * 4;
        if (o < nv4) {
            vint4 s = __builtin_nontemporal_load((const vint4*)(src + e0 + o));
            vint4 d = *(const vint4*)(dst + e0 + o);
            unsigned b, p;
            b = ((unsigned)d.x) >> 12; p = atomicAdd(&sh_hist[b], 1u);
            sh_sorted[p] = ((unsigned)s.x << 12) | ((unsigned)d.x & 4095u); sh_bin[p] = (unsigned char)b;
            b = ((unsigned)d.y) >> 12; p = atomicAdd(&sh_hist[b], 1u);
            sh_sorted[p] = ((unsigned)s.y << 12) | ((unsigned)d.y & 4095u); sh_bin[p] = (unsigned char)b;
            b = ((unsigned)d.z) >> 12; p = atomicAdd(&sh_hist[b], 1u);
            sh_sorted[p] = ((unsigned)s.z << 12) | ((unsigned)d.z & 4095u); sh_bin[p] = (unsigned char)b;
            b = ((unsigned)d.w) >> 12; p = atomicAdd(&sh_hist[b], 1u);
            sh_sorted[p] = ((unsigned)s.w << 12) | ((unsigned)d.w & 4095u); sh_bin[p] = (unsigned char)b;
        }
    }
    for (int j = nv4 + tid; j < n; j += PTHREADS) {
        unsigned dv = (unsigned)dst[e0 + j], sv = (unsigned)src[e0 + j];
        unsigned b = dv >> 12;
        unsigned p = atomicAdd(&sh_hist[b], 1u);
        sh_sorted[p] = (sv << 12) | (dv & 4095u);
        sh_bin[p] = (unsigned char)b;
    }
    __syncthreads();

    // phase 4: coalesced copy-out via direct bin lookup
    for (int t = tid; t < n; t += PTHREADS)
        gsorted[sh_delta[sh_bin[t]] + (unsigned)t] = sh_sorted[t];
}

// per-(dst-bucket, src-bucket) counts
__global__ __launch_bounds__(256)
void k_hist2(const unsigned int* __restrict__ gsorted, const unsigned int* __restrict__ gcur,
             unsigned int* __restrict__ cnt2, unsigned int CAP) {
    __shared__ unsigned int h[NBINS];
    const int tid = threadIdx.x;
    const int b = blockIdx.x;
    const unsigned base = (unsigned)b * CAP;
    const unsigned cnt = gcur[b] - base;
    const unsigned s0 = blockIdx.y * (unsigned)H2CHUNK;
    if (s0 >= cnt) return;
    h[tid] = 0u;
    __syncthreads();
    const unsigned n = min(cnt - s0, (unsigned)H2CHUNK);
    const unsigned* q = gsorted + base + s0;
    const unsigned nv = n >> 2;
    const vuint4* qv = (const vuint4*)q;
    for (unsigned k = tid; k < nv; k += 256u) {
        vuint4 r = __builtin_nontemporal_load(qv + k);
        atomicAdd(&h[r.x >> 24], 1u);
        atomicAdd(&h[r.y >> 24], 1u);
        atomicAdd(&h[r.z >> 24], 1u);
        atomicAdd(&h[r.w >> 24], 1u);
    }
    for (unsigned i = (nv << 2) + tid; i < n; i += 256u)
        atomicAdd(&h[q[i] >> 24], 1u);
    __syncthreads();
    unsigned v = h[tid];
    if (v) atomicAdd(&cnt2[b * NBINS + tid], v);
}

// per-bucket exclusive scan of 256 src-bucket counts -> segment starts
__global__ __launch_bounds__(NBINS)
void k_scan2(const unsigned int* __restrict__ cnt2, unsigned int* __restrict__ gstart2,
             unsigned int* __restrict__ gcur2, unsigned int CAP) {
    __shared__ unsigned int sc[NBINS];
    const int tid = threadIdx.x, b = blockIdx.x;
    unsigned c = cnt2[b * NBINS + tid];
    sc[tid] = c;
    __syncthreads();
    for (int off = 1; off < NBINS; off <<= 1) {
        unsigned v = (tid >= off) ? sc[tid - off] : 0u;
        __syncthreads();
        sc[tid] += v;
        __syncthreads();
    }
    unsigned start = (unsigned)b * CAP + sc[tid] - c;
    gstart2[b * NBINS + tid] = start;
    gcur2[b * NBINS + tid]  = start;
}

// pass 2 of radix: within each dst-bucket, sort records by src-bucket
__global__ __launch_bounds__(PTHREADS)
void k_permute2(const unsigned int* __restrict__ gsorted, const unsigned int* __restrict__ gcur,
                unsigned int* __restrict__ gsorted2, unsigned int* __restrict__ gcur2,
                unsigned int CAP) {
    __shared__ unsigned int  sh_out[P2CHUNK];    // 32 KB
    __shared__ unsigned char sh_bin[P2CHUNK];    //  8 KB
    __shared__ unsigned int  sh_hist[NBINS];
    __shared__ unsigned int  sh_loff[NBINS];
    __shared__ unsigned int  sh_delta[NBINS];
    __shared__ unsigned int  sh_scan[NBINS];
    const int tid = threadIdx.x;
    const int b = blockIdx.x;
    const unsigned base = (unsigned)b * CAP;
    const unsigned cnt = gcur[b] - base;
    const unsigned s0 = blockIdx.y * (unsigned)P2CHUNK;
    if (s0 >= cnt) return;
    const int n = (int)min(cnt - s0, (unsigned)P2CHUNK);
    const unsigned* q = gsorted + base + s0;
    const int nv4 = (n >> 2) << 2;

    if (tid < NBINS) sh_hist[tid] = 0u;
    __syncthreads();

    // phase 1: histogram by src-bucket (cached; phase-3 re-read hits L2)
    #pragma unroll
    for (int k = 0; k < P2CHUNK / (PTHREADS * 4); ++k) {
        int o = (k * PTHREADS + tid) * 4;
        if (o < nv4) {
            vuint4 r = *(const vuint4*)(q + o);
            atomicAdd(&sh_hist[r.x >> 24], 1u);
            atomicAdd(&sh_hist[r.y >> 24], 1u);
            atomicAdd(&sh_hist[r.z >> 24], 1u);
            atomicAdd(&sh_hist[r.w >> 24], 1u);
        }
    }
    for (int j = nv4 + tid; j < n; j += PTHREADS)
        atomicAdd(&sh_hist[q[j] >> 24], 1u);
    __syncthreads();

    // phase 2: scan + exact range reservation in this bucket's segments
    if (tid < NBINS) sh_scan[tid] = sh_hist[tid];
    __syncthreads();
    for (int off = 1; off < NBINS; off <<= 1) {
        unsigned v = 0;
        if (tid < NBINS && tid >= off) v = sh_scan[tid - off];
        __syncthreads();
        if (tid < NBINS) sh_scan[tid] += v;
        __syncthreads();
    }
    if (tid < NBINS) {
        unsigned h = sh_hist[tid];
        unsigned lo = sh_scan[tid] - h;
        sh_loff[tid] = lo;
        if (h) sh_delta[tid] = atomicAdd(&gcur2[b * NBINS + tid], h) - lo;
    }
    __syncthreads();
    if (tid < NBINS) sh_hist[tid] = sh_loff[tid];
    __syncthreads();

    // phase 3: re-read, scatter into LDS in src-bucket order
    #pragma unroll
    for (int k = 0; k < P2CHUNK / (PTHREADS * 4); ++k) {
        int o = (k * PTHREADS + tid) * 4;
        if (o < nv4) {
            vuint4 r = *(const vuint4*)(q + o);
            unsigned bb, p;
            bb = r.x >> 24; p = atomicAdd(&sh_hist[bb], 1u); sh_out[p] = r.x; sh_bin[p] = (unsigned char)bb;
            bb = r.y >> 24; p = atomicAdd(&sh_hist[bb], 1u); sh_out[p] = r.y; sh_bin[p] = (unsigned char)bb;
            bb = r.z >> 24; p = atomicAdd(&sh_hist[bb], 1u); sh_out[p] = r.z; sh_bin[p] = (unsigned char)bb;
            bb = r.w >> 24; p = atomicAdd(&sh_hist[bb], 1u); sh_out[p] = r.w; sh_bin[p] = (unsigned char)bb;
        }
    }
    for (int j = nv4 + tid; j < n; j += PTHREADS) {
        unsigned r = q[j];
        unsigned bb = r >> 24;
        unsigned p = atomicAdd(&sh_hist[bb], 1u);
        sh_out[p] = r; sh_bin[p] = (unsigned char)bb;
    }
    __syncthreads();

    // phase 4: coalesced copy-out
    for (int t = tid; t < n; t += PTHREADS)
        gsorted2[sh_delta[sh_bin[t]] + (unsigned)t] = sh_out[t];
}

// pass 1 aggregate, tiled: for each src-bucket segment, stage the 16KB m-tile
// in LDS; every edge is LDS-read + LDS-atomicAdd. No random global requests.
__global__ __launch_bounds__(1024)
void k_agg1t(const unsigned int* __restrict__ gsorted2,
             const unsigned int* __restrict__ gstart2, const unsigned int* __restrict__ gcur2,
             const float* __restrict__ m, float* __restrict__ y, int N) {
    __shared__ float yloc[BNODES];   // 16 KB
    __shared__ float mt[BNODES];     // 16 KB m-tile
    const int tid = threadIdx.x;
    const int b = blockIdx.x;
    const int s = blockIdx.y;
    for (int j = tid; j < BNODES; j += 1024) yloc[j] = 0.0f;
    const int sb0 = s * (NBINS / SPLITS);
    for (int sb = sb0; sb < sb0 + NBINS / SPLITS; ++sb) {
        const unsigned st = gstart2[b * NBINS + sb];
        const unsigned en = gcur2[b * NBINS + sb];
        if (st == en) continue;                      // uniform
        const int nb = sb << 12;
        {
            int j = tid << 2;
            int gi = nb + j;
            if (gi + 3 < N) {
                *(float4*)(mt + j) = *(const float4*)(m + gi);
            } else {
                #pragma unroll
                for (int u = 0; u < 4; ++u) mt[j + u] = (gi + u < N) ? m[gi + u] : 0.0f;
            }
        }
        __syncthreads();
        for (unsigned i = st + tid; i < en; i += 1024u) {
            unsigned r = __builtin_nontemporal_load(gsorted2 + i);
            atomicAdd(&yloc[r & 4095u], mt[(r >> 12) & 4095u]);
        }
        __syncthreads();
    }
    __syncthreads();
    const int nbase = b * BNODES;
    for (int j = tid; j < BNODES; j += 1024) {
        float v = yloc[j];
        int node = nbase + j;
        if (node < N && v != 0.0f) unsafeAtomicAdd(&y[node], v);
    }
}

// classify: pack 16 node classes per u32 word (2 bits each), zero pk.
// pk aliases y (read y first, then overwrite with 0) — each thread owns
// its 16 slots exclusively, so the alias is safe.
__global__ __launch_bounds__(256)
void k_classify2(const float* __restrict__ y, unsigned int* __restrict__ cls2,
                 unsigned int* __restrict__ pk, int N) {
    int i = blockIdx.x * 256 + threadIdx.x;   // word index
    int nw = (N + 15) >> 4;
    if (i >= nw) return;
    int n0 = i << 4;
    unsigned w = 0u;
    if (n0 + 16 <= N) {
        const float4* yv = (const float4*)(y + n0);
        float4 v0 = yv[0], v1 = yv[1], v2 = yv[2], v3 = yv[3];
        float vv[16] = {v0.x, v0.y, v0.z, v0.w, v1.x, v1.y, v1.z, v1.w,
                        v2.x, v2.y, v2.z, v2.w, v3.x, v3.y, v3.z, v3.w};
        #pragma unroll
        for (int j = 0; j < 16; ++j) {
            unsigned c = (vv[j] > 0.0f) ? 1u : ((vv[j] < 0.0f) ? 2u : 0u);
            w |= c << (j * 2);
        }
        int4 z = {0, 0, 0, 0};
        int4* pz = (int4*)(pk + n0);
        pz[0] = z; pz[1] = z; pz[2] = z; pz[3] = z;
    } else {
        for (int j = 0; n0 + j < N; ++j) {
            float v = y[n0 + j];
            unsigned c = (v > 0.0f) ? 1u : ((v < 0.0f) ? 2u : 0u);
            w |= c << (j * 2);
            pk[n0 + j] = 0u;
        }
    }
    cls2[i] = w;
}

// pass 2 aggregate, tiled: per src-bucket, stage 256 cls words (1KB) in LDS.
__global__ __launch_bounds__(1024)
void k_agg2t(const unsigned int* __restrict__ gsorted2,
             const unsigned int* __restrict__ gstart2, const unsigned int* __restrict__ gcur2,
             const unsigned int* __restrict__ cls2, unsigned int* __restrict__ pk, int N) {
    __shared__ unsigned int pkloc[BNODES];   // 16 KB
    __shared__ unsigned int ct[NBINS];       //  1 KB cls-tile
    const int tid = threadIdx.x;
    const int b = blockIdx.x;
    const int s = blockIdx.y;
    for (int j = tid; j < BNODES; j += 1024) pkloc[j] = 0u;
    const int nw = (N + 15) >> 4;
    const int sb0 = s * (NBINS / SPLITS);
    for (int sb = sb0; sb < sb0 + NBINS / SPLITS; ++sb) {
        const unsigned st = gstart2[b * NBINS + sb];
        const unsigned en = gcur2[b * NBINS + sb];
        if (st == en) continue;                      // uniform
        if (tid < NBINS) {
            int wi = (sb << 8) + tid;
            ct[tid] = (wi < nw) ? cls2[wi] : 0u;
        }
        __syncthreads();
        for (unsigned i = st + tid; i < en; i += 1024u) {
            unsigned r = __builtin_nontemporal_load(gsorted2 + i);
            unsigned sl = (r >> 12) & 4095u;
            unsigned wd = ct[sl >> 4];
            unsigned cl = (wd >> ((sl & 15u) << 1)) & 3u;
            unsigned d = ((cl & 1u) << 16) | (cl >> 1);
            if (d) atomicAdd(&pkloc[r & 4095u], d);
        }
        __syncthreads();
    }
    __syncthreads();
    const int nbase = b * BNODES;
    for (int j = tid; j < BNODES; j += 1024) {
        unsigned v = pkloc[j];
        int node = nbase + j;
        if (node < N && v) atomicAdd(&pk[node], v);
    }
}

// ============ tier-2 agg kernels (R6, gather-based; need only gsorted) ============

__global__ __launch_bounds__(1024)
void k_agg1g(const unsigned int* __restrict__ gsorted, const unsigned int* __restrict__ gcur,
             const float* __restrict__ m, float* __restrict__ y,
             int N, unsigned int CAP, int NB) {
    __shared__ float yloc[BNODES];
    const int tid = threadIdx.x;
    const int b = blockIdx.x % NB;
    const int split = blockIdx.x / NB;
    for (int j = tid; j < BNODES; j += 1024) yloc[j] = 0.0f;
    __syncthreads();
    const unsigned base = (unsigned)b * CAP;
    const unsigned cnt = gcur[b] - base;
    const unsigned nv = cnt >> 2;
    const vuint4* pv = (const vuint4*)(gsorted + base);
    const unsigned stride = SPLITS * 1024u;
    unsigned k = (unsigned)split * 1024u + (unsigned)tid;
    for (; k < nv; k += stride) {
        vuint4 p = __builtin_nontemporal_load(pv + k);
        atomicAdd(&yloc[p.x & 4095u], m[p.x >> 12]);
        atomicAdd(&yloc[p.y & 4095u], m[p.y >> 12]);
        atomicAdd(&yloc[p.z & 4095u], m[p.z >> 12]);
        atomicAdd(&yloc[p.w & 4095u], m[p.w >> 12]);
    }
    if (split == 0) {
        for (unsigned i = (nv << 2) + tid; i < cnt; i += 1024) {
            unsigned p = gsorted[base + i];
            atomicAdd(&yloc[p & 4095u], m[p >> 12]);
        }
    }
    __syncthreads();
    const int nbase = b * BNODES;
    for (int j = tid; j < BNODES; j += 1024) {
        float v = yloc[j];
        int node = nbase + j;
        if (node < N && v != 0.0f) unsafeAtomicAdd(&y[node], v);
    }
}

__global__ __launch_bounds__(1024)
void k_agg2s(const unsigned int* __restrict__ gsorted, const unsigned int* __restrict__ gcur,
             const unsigned int* __restrict__ cls2, unsigned int* __restrict__ pk,
             int N, unsigned int CAP, int NB) {
    __shared__ unsigned int pkloc[BNODES];
    const int tid = threadIdx.x;
    const int b = blockIdx.x % NB;
    const int split = blockIdx.x / NB;
    for (int j = tid; j < BNODES; j += 1024) pkloc[j] = 0u;
    __syncthreads();
    const unsigned base = (unsigned)b * CAP;
    const unsigned cnt = gcur[b] - base;
    const unsigned nv = cnt >> 2;
    const vuint4* pv = (const vuint4*)(gsorted + base);
    auto dec = [&](unsigned s) -> unsigned int {
        unsigned wd = cls2[s >> 4];
        unsigned cl = (wd >> ((s & 15u) << 1)) & 3u;
        return ((cl & 1u) << 16) | (cl >> 1);
    };
    const unsigned stride = SPLITS * 1024u;
    unsigned k = (unsigned)split * 1024u + (unsigned)tid;
    for (; k < nv; k += stride) {
        vuint4 p = __builtin_nontemporal_load(pv + k);
        atomicAdd(&pkloc[p.x & 4095u], dec(p.x >> 12));
        atomicAdd(&pkloc[p.y & 4095u], dec(p.y >> 12));
        atomicAdd(&pkloc[p.z & 4095u], dec(p.z >> 12));
        atomicAdd(&pkloc[p.w & 4095u], dec(p.w >> 12));
    }
    if (split == 0) {
        for (unsigned i = (nv << 2) + tid; i < cnt; i += 1024) {
            unsigned p = gsorted[base + i];
            atomicAdd(&pkloc[p & 4095u], dec(p >> 12));
        }
    }
    __syncthreads();
    const int nbase = b * BNODES;
    for (int j = tid; j < BNODES; j += 1024) {
        unsigned v = pkloc[j];
        int node = nbase + j;
        if (node < N && v) atomicAdd(&pk[node], v);
    }
}

// ===================== fallback path (R3, atomic-based) =====================

__global__ __launch_bounds__(256)
void k_prep(const float2* __restrict__ x, const float* __restrict__ W,
            float* __restrict__ m, float* __restrict__ y,
            unsigned int* __restrict__ pk, int N) {
    int i = blockIdx.x * blockDim.x + threadIdx.x;
    if (i < N) {
        float2 v = x[i];
        float inv = 1.0f / (sqrtf(v.x * v.x + v.y * v.y) + EPS);
        m[i]  = (v.x * inv) * W[0] + (v.y * inv) * W[2];
        y[i]  = 0.0f;
        pk[i] = 0u;
    }
}

__global__ __launch_bounds__(256)
void k_scatter1(const int* __restrict__ src, const int* __restrict__ dst,
                const float* __restrict__ m, float* __restrict__ y, int E) {
    int t = blockIdx.x * blockDim.x + threadIdx.x;
    int i = t * 8;
    if (i + 8 <= E) {
        vint4 s0 = __builtin_nontemporal_load((const vint4*)(src + i));
        vint4 s1 = __builtin_nontemporal_load((const vint4*)(src + i + 4));
        vint4 d0 = __builtin_nontemporal_load((const vint4*)(dst + i));
        vint4 d1 = __builtin_nontemporal_load((const vint4*)(dst + i + 4));
        unsafeAtomicAdd(&y[d0.x], m[s0.x]);
        unsafeAtomicAdd(&y[d0.y], m[s0.y]);
        unsafeAtomicAdd(&y[d0.z], m[s0.z]);
        unsafeAtomicAdd(&y[d0.w], m[s0.w]);
        unsafeAtomicAdd(&y[d1.x], m[s1.x]);
        unsafeAtomicAdd(&y[d1.y], m[s1.y]);
        unsafeAtomicAdd(&y[d1.z], m[s1.z]);
        unsafeAtomicAdd(&y[d1.w], m[s1.w]);
    } else if (i < E) {
        for (int j = i; j < E; ++j)
            unsafeAtomicAdd(&y[dst[j]], m[src[j]]);
    }
}

__global__ __launch_bounds__(256)
void k_classify(const float* __restrict__ y, unsigned char* __restrict__ cls, int N) {
    int i = blockIdx.x * blockDim.x + threadIdx.x;
    if (i < N) {
        float v = y[i];
        cls[i] = (v > 0.0f) ? 1 : ((v < 0.0f) ? 2 : 0);
    }
}

__global__ __launch_bounds__(256)
void k_scatter2(const int* __restrict__ src, const int* __restrict__ dst,
                const unsigned char* __restrict__ cls, unsigned int* __restrict__ pk,
                int E) {
    int t = blockIdx.x * blockDim.x + threadIdx.x;
    int i = t * 8;
    auto dec = [](unsigned char c) -> unsigned int {
        return (c == 1) ? 65536u : ((c == 2) ? 1u : 0u);
    };
    if (i + 8 <= E) {
        vint4 s0 = __builtin_nontemporal_load((const vint4*)(src + i));
        vint4 s1 = __builtin_nontemporal_load((const vint4*)(src + i + 4));
        vint4 d0 = __builtin_nontemporal_load((const vint4*)(dst + i));
        vint4 d1 = __builtin_nontemporal_load((const vint4*)(dst + i + 4));
        atomicAdd(&pk[d0.x], dec(cls[s0.x]));
        atomicAdd(&pk[d0.y], dec(cls[s0.y]));
        atomicAdd(&pk[d0.z], dec(cls[s0.z]));
        atomicAdd(&pk[d0.w], dec(cls[s0.w]));
        atomicAdd(&pk[d1.x], dec(cls[s1.x]));
        atomicAdd(&pk[d1.y], dec(cls[s1.y]));
        atomicAdd(&pk[d1.z], dec(cls[s1.z]));
        atomicAdd(&pk[d1.w], dec(cls[s1.w]));
    } else if (i < E) {
        for (int j = i; j < E; ++j)
            atomicAdd(&pk[dst[j]], dec(cls[src[j]]));
    }
}

__global__ __launch_bounds__(256)
void k_final(const unsigned int* __restrict__ pk, const float* __restrict__ W,
             const float* __restrict__ fw, float* __restrict__ out, int N) {
    int i = blockIdx.x * blockDim.x + threadIdx.x;
    if (i < N) {
        unsigned p = pk[i];
        float c0 = (float)(p >> 16);
        float c1 = (float)(p & 0xFFFFu);
        float x0 = fmaxf(c0 * W[0] + c1 * W[2], 0.0f);
        float x1 = fmaxf(c0 * W[1] + c1 * W[3], 0.0f);
        float z = x0 * fw[0] + x1 * fw[1];
        out[i] = 1.0f / (1.0f + expf(-z));
    }
}

// ===================== launch =====================

extern "C" void kernel_launch(void* const* d_in, const int* in_sizes, int n_in,
                              void* d_out, int out_size, void* d_ws, size_t ws_size,
                              hipStream_t stream) {
    const float* x  = (const float*)d_in[0];
    const int*   ei = (const int*)d_in[1];
    const float* W  = (const float*)d_in[2];
    const float* fw = (const float*)d_in[3];
    float*       out = (float*)d_out;

    const int N = in_sizes[0] / 2;
    const int E = in_sizes[1] / 2;
    const int* src = ei;
    const int* dst = ei + E;

    const int B  = 256;
    const int gN = (N + B - 1) / B;

    // sort-path sizing: 256 bins of 4096 nodes
    const int NB = (N + BNODES - 1) / BNODES;
    double mean = (double)E / ((double)N / (double)BNODES);
    unsigned CAP = (unsigned)(mean + 8.0 * sqrt(mean) + 1024.0);
    CAP = (CAP + 1023u) & ~1023u;

    const int NW = (N + 15) >> 4;   // packed class words

    char* p = (char*)d_ws;
    float*         m_s   = (float*)p;          p += (((size_t)N * 4 + 255) & ~255ULL);
    unsigned int*  gcur  = (unsigned int*)p;   p += (((size_t)NB * 4 + 255) & ~255ULL);
    float*         y_s   = (float*)p;          p += (((size_t)N * 4 + 255) & ~255ULL);
    unsigned int*  cls2  = (unsigned int*)p;   p += (((size_t)NW * 4 + 255) & ~255ULL);
    unsigned int*  cnt2    = (unsigned int*)p; p += (size_t)NBINS * NBINS * 4;
    unsigned int*  gstart2 = (unsigned int*)p; p += (size_t)NBINS * NBINS * 4;
    unsigned int*  gcur2   = (unsigned int*)p; p += (size_t)NBINS * NBINS * 4;
    unsigned int*  gsorted = (unsigned int*)p;
    size_t sorted_bytes = (size_t)NB * CAP * 4ULL;
    unsigned int*  gsorted2 = (unsigned int*)(p + ((sorted_bytes + 255) & ~255ULL));
    size_t fixed = (size_t)(p - (char*)d_ws);
    size_t need_t2 = fixed + sorted_bytes;
    size_t need_t1 = fixed + ((sorted_bytes + 255) & ~255ULL) + sorted_bytes;

    if (ws_size >= need_t2 && N <= (1 << 20) && NB <= NBINS) {
        const bool tier1 = (ws_size >= need_t1);
        const int gP = (E + CHUNK - 1) / CHUNK;
        unsigned int* pk_s = (unsigned int*)y_s;   // pk aliases y (see k_classify2)
        k_prep2<<<gN, B, 0, stream>>>((const float2*)x, W, m_s, y_s, gcur,
                                      tier1 ? cnt2 : nullptr, N, NB, CAP);
        k_permute<<<gP, PTHREADS, 0, stream>>>(src, dst, gsorted, gcur, E);
        if (tier1) {
            const int HS = (int)((CAP + H2CHUNK - 1) / H2CHUNK);
            const int PS = (int)((CAP + P2CHUNK - 1) / P2CHUNK);
            k_hist2<<<dim3(NB, HS), 256, 0, stream>>>(gsorted, gcur, cnt2, CAP);
            k_scan2<<<NB, NBINS, 0, stream>>>(cnt2, gstart2, gcur2, CAP);
            k_permute2<<<dim3(NB, PS), PTHREADS, 0, stream>>>(gsorted, gcur, gsorted2, gcur2, CAP);
            k_agg1t<<<dim3(NB, SPLITS), 1024, 0, stream>>>(gsorted2, gstart2, gcur2, m_s, y_s, N);
            k_classify2<<<(NW + B - 1) / B, B, 0, stream>>>(y_s, cls2, pk_s, N);
            k_agg2t<<<dim3(NB, SPLITS), 1024, 0, stream>>>(gsorted2, gstart2, gcur2, cls2, pk_s, N);
        } else {
            k_agg1g<<<NB * SPLITS, 1024, 0, stream>>>(gsorted, gcur, m_s, y_s, N, CAP, NB);
            k_classify2<<<(NW + B - 1) / B, B, 0, stream>>>(y_s, cls2, pk_s, N);
            k_agg2s<<<NB * SPLITS, 1024, 0, stream>>>(gsorted, gcur, cls2, pk_s, N, CAP, NB);
        }
        k_final<<<gN, B, 0, stream>>>(pk_s, W, fw, out, N);
    } else {
        // fallback: R3 atomic path
        char* q = (char*)d_ws;
        unsigned char* cls = (unsigned char*)q;  q += (((size_t)N + 255) & ~255ULL);
        float*         m   = (float*)q;          q += (((size_t)N * 4 + 255) & ~255ULL);
        float*         y   = (float*)q;          q += (((size_t)N * 4 + 255) & ~255ULL);
        unsigned int*  pk  = (unsigned int*)q;
        const int gE = (E / 8 + B - 1) / B + 1;
        k_prep<<<gN, B, 0, stream>>>((const float2*)x, W, m, y, pk, N);
        k_scatter1<<<gE, B, 0, stream>>>(src, dst, m, y, E);
        k_classify<<<gN, B, 0, stream>>>(y, cls, N);
        k_scatter2<<<gE, B, 0, stream>>>(src, dst, cls, pk, E);
        k_final<<<gN, B, 0, stream>>>(pk, W, fw, out, N);
    }
}

// Round 4
// 822.841 us; speedup vs baseline: 1.1846x; 1.1179x over previous
//
#include <hip/hip_runtime.h>
#include <math.h>

// N=1M nodes, E=32M edges. Two-level counting sort (dst-bucket, then
// src-bucket within), so both aggregation passes are pure sequential streams
// + LDS-resident tiles + LDS atomics. History:
//  R5-R6: single-level sort; agg passes pinned at 183us = 32M per-lane random
//         gather requests (~175 G req/s), invariant to occupancy/table size.
//  R7: gather moved into permute -> thrashed L2, regressed. Reverted.
//  R8: two-level sort + tiled agg, but 512-record segments with 2 barriers
//      and a synchronous 16KB tile load per phase -> 272us (phase-serialized).
//  R9 (this round): 8192-node src-buckets (128 bins, mean segment 1024 recs
//      = 1 full block-iteration), double-buffered tile prefetch (issue loads
//      -> process records -> store to LDS), ONE barrier per phase.
//
// record = (src << 12) | (dst & 4095)   [src < 2^20, src-bucket = rec>>25]
// ws: m (4MB) | gcur (1KB) | y/pk alias (4MB) | cls2 (256KB)
//     | cnt2/gstart2/gcur2 (3x256KB) | gsorted (~132MB) | gsorted2 (~132MB)

#define EPS 1e-15f
#define CHUNK 8192      // permute1 edges/block
#define P2CHUNK 8192    // permute2 records/block
#define H2CHUNK 32768   // hist2 records/block
#define PTHREADS 512
#define NBINS 256       // dst-bucket bins (4096 nodes each)
#define NB2 128         // src-bucket bins (8192 nodes each)
#define BNODES 4096
#define SPLITS 4        // agg blocks per dst-bucket (each owns 32 src-buckets)

typedef int          vint4  __attribute__((ext_vector_type(4)));
typedef unsigned int vuint4 __attribute__((ext_vector_type(4)));

__device__ inline float4 ld_m4(const float* __restrict__ m, int gi, int N) {
    if (gi + 3 < N) return *(const float4*)(m + gi);
    float4 v; v.x = v.y = v.z = v.w = 0.0f;
    if (gi     < N) v.x = m[gi];
    if (gi + 1 < N) v.y = m[gi + 1];
    if (gi + 2 < N) v.z = m[gi + 2];
    return v;
}

// ===================== sort path =====================

__global__ __launch_bounds__(256)
void k_prep2(const float2* __restrict__ x, const float* __restrict__ W,
             float* __restrict__ m, float* __restrict__ y,
             unsigned int* __restrict__ gcur, unsigned int* __restrict__ cnt2,
             int N, int NB, unsigned int CAP, int n2) {
    int i = blockIdx.x * 256 + threadIdx.x;
    if (i < N) {
        float2 v = x[i];
        float inv = 1.0f / (sqrtf(v.x * v.x + v.y * v.y) + EPS);
        m[i] = (v.x * inv) * W[0] + (v.y * inv) * W[2];
        y[i] = 0.0f;
    }
    if (i < NB) gcur[i] = (unsigned)i * CAP;
    if (cnt2 && i < n2) cnt2[i] = 0u;
}

// pass 1 of radix: counting sort by dst-bucket (R6-proven form)
__global__ __launch_bounds__(PTHREADS)
void k_permute(const int* __restrict__ src, const int* __restrict__ dst,
               unsigned int* __restrict__ gsorted, unsigned int* __restrict__ gcur,
               int E) {
    __shared__ unsigned int  sh_sorted[CHUNK];   // 32 KB staged records
    __shared__ unsigned char sh_bin[CHUNK];      //  8 KB bin of each slot
    __shared__ unsigned int  sh_hist[NBINS];
    __shared__ unsigned int  sh_loff[NBINS];
    __shared__ unsigned int  sh_delta[NBINS];
    __shared__ unsigned int  sh_scan[NBINS];
    const int tid = threadIdx.x;
    const long long e0 = (long long)blockIdx.x * CHUNK;
    const int n = (int)min((long long)CHUNK, (long long)E - e0);
    const int nv4 = (n >> 2) << 2;

    if (tid < NBINS) sh_hist[tid] = 0u;
    __syncthreads();

    // phase 1: bucket histogram of dst (cached loads; phase-3 re-read hits L2)
    #pragma unroll
    for (int k = 0; k < CHUNK / (PTHREADS * 4); ++k) {
        int o = (k * PTHREADS + tid) * 4;
        if (o < nv4) {
            vint4 d = *(const vint4*)(dst + e0 + o);
            atomicAdd(&sh_hist[((unsigned)d.x) >> 12], 1u);
            atomicAdd(&sh_hist[((unsigned)d.y) >> 12], 1u);
            atomicAdd(&sh_hist[((unsigned)d.z) >> 12], 1u);
            atomicAdd(&sh_hist[((unsigned)d.w) >> 12], 1u);
        }
    }
    for (int j = nv4 + tid; j < n; j += PTHREADS)
        atomicAdd(&sh_hist[((unsigned)dst[e0 + j]) >> 12], 1u);
    __syncthreads();

    // phase 2: scan 256 bins + global range reservation
    if (tid < NBINS) sh_scan[tid] = sh_hist[tid];
    __syncthreads();
    for (int off = 1; off < NBINS; off <<= 1) {
        unsigned v = 0;
        if (tid < NBINS && tid >= off) v = sh_scan[tid - off];
        __syncthreads();
        if (tid < NBINS) sh_scan[tid] += v;
        __syncthreads();
    }
    if (tid < NBINS) {
        unsigned h = sh_hist[tid];
        unsigned lo = sh_scan[tid] - h;     // exclusive prefix
        sh_loff[tid] = lo;
        if (h) sh_delta[tid] = atomicAdd(&gcur[tid], h) - lo;
    }
    __syncthreads();
    if (tid < NBINS) sh_hist[tid] = sh_loff[tid];   // running cursor
    __syncthreads();

    // phase 3: re-read src+dst, scatter packed records into LDS in bin order
    #pragma unroll
    for (int k = 0; k < CHUNK / (PTHREADS * 4); ++k) {
        int o = (k * PTHREADS + tid) * 4;
        if (o < nv4) {
            vint4 s = __builtin_nontemporal_load((const vint4*)(src + e0 + o));
            vint4 d = *(const vint4*)(dst + e0 + o);
            unsigned b, p;
            b = ((unsigned)d.x) >> 12; p = atomicAdd(&sh_hist[b], 1u);
            sh_sorted[p] = ((unsigned)s.x << 12) | ((unsigned)d.x & 4095u); sh_bin[p] = (unsigned char)b;
            b = ((unsigned)d.y) >> 12; p = atomicAdd(&sh_hist[b], 1u);
            sh_sorted[p] = ((unsigned)s.y << 12) | ((unsigned)d.y & 4095u); sh_bin[p] = (unsigned char)b;
            b = ((unsigned)d.z) >> 12; p = atomicAdd(&sh_hist[b], 1u);
            sh_sorted[p] = ((unsigned)s.z << 12) | ((unsigned)d.z & 4095u); sh_bin[p] = (unsigned char)b;
            b = ((unsigned)d.w) >> 12; p = atomicAdd(&sh_hist[b], 1u);
            sh_sorted[p] = ((unsigned)s.w << 12) | ((unsigned)d.w & 4095u); sh_bin[p] = (unsigned char)b;
        }
    }
    for (int j = nv4 + tid; j < n; j += PTHREADS) {
        unsigned dv = (unsigned)dst[e0 + j], sv = (unsigned)src[e0 + j];
        unsigned b = dv >> 12;
        unsigned p = atomicAdd(&sh_hist[b], 1u);
        sh_sorted[p] = (sv << 12) | (dv & 4095u);
        sh_bin[p] = (unsigned char)b;
    }
    __syncthreads();

    // phase 4: coalesced copy-out via direct bin lookup
    for (int t = tid; t < n; t += PTHREADS)
        gsorted[sh_delta[sh_bin[t]] + (unsigned)t] = sh_sorted[t];
}

// per-(dst-bucket, src-bucket) counts
__global__ __launch_bounds__(256)
void k_hist2(const unsigned int* __restrict__ gsorted, const unsigned int* __restrict__ gcur,
             unsigned int* __restrict__ cnt2, unsigned int CAP) {
    __shared__ unsigned int h[NB2];
    const int tid = threadIdx.x;
    const int b = blockIdx.x;
    const unsigned base = (unsigned)b * CAP;
    const unsigned cnt = gcur[b] - base;
    const unsigned s0 = blockIdx.y * (unsigned)H2CHUNK;
    if (s0 >= cnt) return;
    if (tid < NB2) h[tid] = 0u;
    __syncthreads();
    const unsigned n = min(cnt - s0, (unsigned)H2CHUNK);
    const unsigned* q = gsorted + base + s0;
    const unsigned nv = n >> 2;
    const vuint4* qv = (const vuint4*)q;
    for (unsigned k = tid; k < nv; k += 256u) {
        vuint4 r = __builtin_nontemporal_load(qv + k);
        atomicAdd(&h[r.x >> 25], 1u);
        atomicAdd(&h[r.y >> 25], 1u);
        atomicAdd(&h[r.z >> 25], 1u);
        atomicAdd(&h[r.w >> 25], 1u);
    }
    for (unsigned i = (nv << 2) + tid; i < n; i += 256u)
        atomicAdd(&h[q[i] >> 25], 1u);
    __syncthreads();
    if (tid < NB2) {
        unsigned v = h[tid];
        if (v) atomicAdd(&cnt2[b * NB2 + tid], v);
    }
}

// per-bucket exclusive scan of 128 src-bucket counts -> segment starts
__global__ __launch_bounds__(NB2)
void k_scan2(const unsigned int* __restrict__ cnt2, unsigned int* __restrict__ gstart2,
             unsigned int* __restrict__ gcur2, unsigned int CAP) {
    __shared__ unsigned int sc[NB2];
    const int tid = threadIdx.x, b = blockIdx.x;
    unsigned c = cnt2[b * NB2 + tid];
    sc[tid] = c;
    __syncthreads();
    for (int off = 1; off < NB2; off <<= 1) {
        unsigned v = (tid >= off) ? sc[tid - off] : 0u;
        __syncthreads();
        sc[tid] += v;
        __syncthreads();
    }
    unsigned start = (unsigned)b * CAP + sc[tid] - c;
    gstart2[b * NB2 + tid] = start;
    gcur2[b * NB2 + tid]  = start;
}

// pass 2 of radix: within each dst-bucket, sort records by src-bucket
__global__ __launch_bounds__(PTHREADS)
void k_permute2(const unsigned int* __restrict__ gsorted, const unsigned int* __restrict__ gcur,
                unsigned int* __restrict__ gsorted2, unsigned int* __restrict__ gcur2,
                unsigned int CAP) {
    __shared__ unsigned int  sh_out[P2CHUNK];    // 32 KB
    __shared__ unsigned char sh_bin[P2CHUNK];    //  8 KB
    __shared__ unsigned int  sh_hist[NB2];
    __shared__ unsigned int  sh_loff[NB2];
    __shared__ unsigned int  sh_delta[NB2];
    __shared__ unsigned int  sh_scan[NB2];
    const int tid = threadIdx.x;
    const int b = blockIdx.x;
    const unsigned base = (unsigned)b * CAP;
    const unsigned cnt = gcur[b] - base;
    const unsigned s0 = blockIdx.y * (unsigned)P2CHUNK;
    if (s0 >= cnt) return;
    const int n = (int)min(cnt - s0, (unsigned)P2CHUNK);
    const unsigned* q = gsorted + base + s0;
    const int nv4 = (n >> 2) << 2;

    if (tid < NB2) sh_hist[tid] = 0u;
    __syncthreads();

    // phase 1: histogram by src-bucket (cached; phase-3 re-read hits L2)
    #pragma unroll
    for (int k = 0; k < P2CHUNK / (PTHREADS * 4); ++k) {
        int o = (k * PTHREADS + tid) * 4;
        if (o < nv4) {
            vuint4 r = *(const vuint4*)(q + o);
            atomicAdd(&sh_hist[r.x >> 25], 1u);
            atomicAdd(&sh_hist[r.y >> 25], 1u);
            atomicAdd(&sh_hist[r.z >> 25], 1u);
            atomicAdd(&sh_hist[r.w >> 25], 1u);
        }
    }
    for (int j = nv4 + tid; j < n; j += PTHREADS)
        atomicAdd(&sh_hist[q[j] >> 25], 1u);
    __syncthreads();

    // phase 2: scan + exact range reservation in this bucket's segments
    if (tid < NB2) sh_scan[tid] = sh_hist[tid];
    __syncthreads();
    for (int off = 1; off < NB2; off <<= 1) {
        unsigned v = 0;
        if (tid < NB2 && tid >= off) v = sh_scan[tid - off];
        __syncthreads();
        if (tid < NB2) sh_scan[tid] += v;
        __syncthreads();
    }
    if (tid < NB2) {
        unsigned h = sh_hist[tid];
        unsigned lo = sh_scan[tid] - h;
        sh_loff[tid] = lo;
        if (h) sh_delta[tid] = atomicAdd(&gcur2[b * NB2 + tid], h) - lo;
    }
    __syncthreads();
    if (tid < NB2) sh_hist[tid] = sh_loff[tid];
    __syncthreads();

    // phase 3: re-read, scatter into LDS in src-bucket order
    #pragma unroll
    for (int k = 0; k < P2CHUNK / (PTHREADS * 4); ++k) {
        int o = (k * PTHREADS + tid) * 4;
        if (o < nv4) {
            vuint4 r = *(const vuint4*)(q + o);
            unsigned bb, p;
            bb = r.x >> 25; p = atomicAdd(&sh_hist[bb], 1u); sh_out[p] = r.x; sh_bin[p] = (unsigned char)bb;
            bb = r.y >> 25; p = atomicAdd(&sh_hist[bb], 1u); sh_out[p] = r.y; sh_bin[p] = (unsigned char)bb;
            bb = r.z >> 25; p = atomicAdd(&sh_hist[bb], 1u); sh_out[p] = r.z; sh_bin[p] = (unsigned char)bb;
            bb = r.w >> 25; p = atomicAdd(&sh_hist[bb], 1u); sh_out[p] = r.w; sh_bin[p] = (unsigned char)bb;
        }
    }
    for (int j = nv4 + tid; j < n; j += PTHREADS) {
        unsigned r = q[j];
        unsigned bb = r >> 25;
        unsigned p = atomicAdd(&sh_hist[bb], 1u);
        sh_out[p] = r; sh_bin[p] = (unsigned char)bb;
    }
    __syncthreads();

    // phase 4: coalesced copy-out
    for (int t = tid; t < n; t += PTHREADS)
        gsorted2[sh_delta[sh_bin[t]] + (unsigned)t] = sh_out[t];
}

// pass 1 aggregate, tiled+pipelined: 32 phases/block; per phase, prefetch
// next 32KB m-tile into regs, process current segment (mean 1024 records,
// coalesced stream load + LDS read + LDS atomic), store prefetch to LDS,
// ONE barrier. 80KB LDS -> 2 blocks/CU.
__global__ __launch_bounds__(1024)
void k_agg1t(const unsigned int* __restrict__ gsorted2,
             const unsigned int* __restrict__ gstart2, const unsigned int* __restrict__ gcur2,
             const float* __restrict__ m, float* __restrict__ y, int N) {
    __shared__ float yloc[BNODES];      // 16 KB
    __shared__ float mt[2][8192];       // 64 KB double-buffered m tiles
    const int tid = threadIdx.x;
    const int b = blockIdx.x;
    const int s = blockIdx.y;
    const int sb0 = s * (NB2 / SPLITS);
    for (int j = tid; j < BNODES; j += 1024) yloc[j] = 0.0f;
    {   // load tile sb0 into mt[0]
        int gi = (sb0 << 13) + (tid << 2);
        *(float4*)&mt[0][tid << 2]          = ld_m4(m, gi, N);
        *(float4*)&mt[0][4096 + (tid << 2)] = ld_m4(m, gi + 4096, N);
    }
    __syncthreads();
    #pragma unroll 1
    for (int p = 0; p < NB2 / SPLITS; ++p) {
        const int cur = p & 1;
        const int sb = sb0 + p;
        const bool pf = (p + 1 < NB2 / SPLITS);
        float4 f0, f1;
        if (pf) {   // issue next-tile loads; latency hides under record loop
            int gi = ((sb + 1) << 13) + (tid << 2);
            f0 = ld_m4(m, gi, N);
            f1 = ld_m4(m, gi + 4096, N);
        }
        const unsigned st = gstart2[b * NB2 + sb];
        const unsigned en = gcur2 [b * NB2 + sb];
        for (unsigned i = st + tid; i < en; i += 1024u) {
            unsigned r = __builtin_nontemporal_load(gsorted2 + i);
            atomicAdd(&yloc[r & 4095u], mt[cur][(r >> 12) & 8191u]);
        }
        if (pf) {
            *(float4*)&mt[cur ^ 1][tid << 2]          = f0;
            *(float4*)&mt[cur ^ 1][4096 + (tid << 2)] = f1;
        }
        __syncthreads();   // next-tile ready AND all reads of mt[cur] done
    }
    const int nbase = b * BNODES;
    for (int j = tid; j < BNODES; j += 1024) {
        float v = yloc[j];
        int node = nbase + j;
        if (node < N && v != 0.0f) unsafeAtomicAdd(&y[node], v);
    }
}

// classify: pack 16 node classes per u32 word (2 bits each), zero pk.
// pk aliases y (read y first, then overwrite with 0) — each thread owns
// its 16 slots exclusively, so the alias is safe.
__global__ __launch_bounds__(256)
void k_classify2(const float* __restrict__ y, unsigned int* __restrict__ cls2,
                 unsigned int* __restrict__ pk, int N) {
    int i = blockIdx.x * 256 + threadIdx.x;   // word index
    int nw = (N + 15) >> 4;
    if (i >= nw) return;
    int n0 = i << 4;
    unsigned w = 0u;
    if (n0 + 16 <= N) {
        const float4* yv = (const float4*)(y + n0);
        float4 v0 = yv[0], v1 = yv[1], v2 = yv[2], v3 = yv[3];
        float vv[16] = {v0.x, v0.y, v0.z, v0.w, v1.x, v1.y, v1.z, v1.w,
                        v2.x, v2.y, v2.z, v2.w, v3.x, v3.y, v3.z, v3.w};
        #pragma unroll
        for (int j = 0; j < 16; ++j) {
            unsigned c = (vv[j] > 0.0f) ? 1u : ((vv[j] < 0.0f) ? 2u : 0u);
            w |= c << (j * 2);
        }
        int4 z = {0, 0, 0, 0};
        int4* pz = (int4*)(pk + n0);
        pz[0] = z; pz[1] = z; pz[2] = z; pz[3] = z;
    } else {
        for (int j = 0; n0 + j < N; ++j) {
            float v = y[n0 + j];
            unsigned c = (v > 0.0f) ? 1u : ((v < 0.0f) ? 2u : 0u);
            w |= c << (j * 2);
            pk[n0 + j] = 0u;
        }
    }
    cls2[i] = w;
}

// pass 2 aggregate, tiled+pipelined like pass 1; cls-tile = 512 words (2KB).
__global__ __launch_bounds__(1024)
void k_agg2t(const unsigned int* __restrict__ gsorted2,
             const unsigned int* __restrict__ gstart2, const unsigned int* __restrict__ gcur2,
             const unsigned int* __restrict__ cls2, unsigned int* __restrict__ pk, int N) {
    __shared__ unsigned int pkloc[BNODES];   // 16 KB
    __shared__ unsigned int ct[2][512];      //  4 KB double-buffered cls tiles
    const int tid = threadIdx.x;
    const int b = blockIdx.x;
    const int s = blockIdx.y;
    const int sb0 = s * (NB2 / SPLITS);
    const int nw = (N + 15) >> 4;
    for (int j = tid; j < BNODES; j += 1024) pkloc[j] = 0u;
    if (tid < 512) {
        int wi = (sb0 << 9) + tid;
        ct[0][tid] = (wi < nw) ? cls2[wi] : 0u;
    }
    __syncthreads();
    #pragma unroll 1
    for (int p = 0; p < NB2 / SPLITS; ++p) {
        const int cur = p & 1;
        const int sb = sb0 + p;
        const bool pf = (p + 1 < NB2 / SPLITS) && (tid < 512);
        unsigned cw = 0u;
        if (pf) {
            int wi = ((sb + 1) << 9) + tid;
            cw = (wi < nw) ? cls2[wi] : 0u;
        }
        const unsigned st = gstart2[b * NB2 + sb];
        const unsigned en = gcur2 [b * NB2 + sb];
        for (unsigned i = st + tid; i < en; i += 1024u) {
            unsigned r = __builtin_nontemporal_load(gsorted2 + i);
            unsigned sl = (r >> 12) & 8191u;
            unsigned wd = ct[cur][sl >> 4];
            unsigned cl = (wd >> ((sl & 15u) << 1)) & 3u;
            unsigned d = ((cl & 1u) << 16) | (cl >> 1);
            atomicAdd(&pkloc[r & 4095u], d);
        }
        if (pf) ct[cur ^ 1][tid] = cw;
        __syncthreads();
    }
    const int nbase = b * BNODES;
    for (int j = tid; j < BNODES; j += 1024) {
        unsigned v = pkloc[j];
        int node = nbase + j;
        if (node < N && v) atomicAdd(&pk[node], v);
    }
}

// ============ tier-2 agg kernels (R6, gather-based; need only gsorted) ============

__global__ __launch_bounds__(1024)
void k_agg1g(const unsigned int* __restrict__ gsorted, const unsigned int* __restrict__ gcur,
             const float* __restrict__ m, float* __restrict__ y,
             int N, unsigned int CAP, int NB) {
    __shared__ float yloc[BNODES];
    const int tid = threadIdx.x;
    const int b = blockIdx.x % NB;
    const int split = blockIdx.x / NB;
    for (int j = tid; j < BNODES; j += 1024) yloc[j] = 0.0f;
    __syncthreads();
    const unsigned base = (unsigned)b * CAP;
    const unsigned cnt = gcur[b] - base;
    const unsigned nv = cnt >> 2;
    const vuint4* pv = (const vuint4*)(gsorted + base);
    const unsigned stride = SPLITS * 1024u;
    unsigned k = (unsigned)split * 1024u + (unsigned)tid;
    for (; k < nv; k += stride) {
        vuint4 p = __builtin_nontemporal_load(pv + k);
        atomicAdd(&yloc[p.x & 4095u], m[p.x >> 12]);
        atomicAdd(&yloc[p.y & 4095u], m[p.y >> 12]);
        atomicAdd(&yloc[p.z & 4095u], m[p.z >> 12]);
        atomicAdd(&yloc[p.w & 4095u], m[p.w >> 12]);
    }
    if (split == 0) {
        for (unsigned i = (nv << 2) + tid; i < cnt; i += 1024) {
            unsigned p = gsorted[base + i];
            atomicAdd(&yloc[p & 4095u], m[p >> 12]);
        }
    }
    __syncthreads();
    const int nbase = b * BNODES;
    for (int j = tid; j < BNODES; j += 1024) {
        float v = yloc[j];
        int node = nbase + j;
        if (node < N && v != 0.0f) unsafeAtomicAdd(&y[node], v);
    }
}

__global__ __launch_bounds__(1024)
void k_agg2s(const unsigned int* __restrict__ gsorted, const unsigned int* __restrict__ gcur,
             const unsigned int* __restrict__ cls2, unsigned int* __restrict__ pk,
             int N, unsigned int CAP, int NB) {
    __shared__ unsigned int pkloc[BNODES];
    const int tid = threadIdx.x;
    const int b = blockIdx.x % NB;
    const int split = blockIdx.x / NB;
    for (int j = tid; j < BNODES; j += 1024) pkloc[j] = 0u;
    __syncthreads();
    const unsigned base = (unsigned)b * CAP;
    const unsigned cnt = gcur[b] - base;
    const unsigned nv = cnt >> 2;
    const vuint4* pv = (const vuint4*)(gsorted + base);
    auto dec = [&](unsigned s) -> unsigned int {
        unsigned wd = cls2[s >> 4];
        unsigned cl = (wd >> ((s & 15u) << 1)) & 3u;
        return ((cl & 1u) << 16) | (cl >> 1);
    };
    const unsigned stride = SPLITS * 1024u;
    unsigned k = (unsigned)split * 1024u + (unsigned)tid;
    for (; k < nv; k += stride) {
        vuint4 p = __builtin_nontemporal_load(pv + k);
        atomicAdd(&pkloc[p.x & 4095u], dec(p.x >> 12));
        atomicAdd(&pkloc[p.y & 4095u], dec(p.y >> 12));
        atomicAdd(&pkloc[p.z & 4095u], dec(p.z >> 12));
        atomicAdd(&pkloc[p.w & 4095u], dec(p.w >> 12));
    }
    if (split == 0) {
        for (unsigned i = (nv << 2) + tid; i < cnt; i += 1024) {
            unsigned p = gsorted[base + i];
            atomicAdd(&pkloc[p & 4095u], dec(p >> 12));
        }
    }
    __syncthreads();
    const int nbase = b * BNODES;
    for (int j = tid; j < BNODES; j += 1024) {
        unsigned v = pkloc[j];
        int node = nbase + j;
        if (node < N && v) atomicAdd(&pk[node], v);
    }
}

// ===================== fallback path (R3, atomic-based) =====================

__global__ __launch_bounds__(256)
void k_prep(const float2* __restrict__ x, const float* __restrict__ W,
            float* __restrict__ m, float* __restrict__ y,
            unsigned int* __restrict__ pk, int N) {
    int i = blockIdx.x * blockDim.x + threadIdx.x;
    if (i < N) {
        float2 v = x[i];
        float inv = 1.0f / (sqrtf(v.x * v.x + v.y * v.y) + EPS);
        m[i]  = (v.x * inv) * W[0] + (v.y * inv) * W[2];
        y[i]  = 0.0f;
        pk[i] = 0u;
    }
}

__global__ __launch_bounds__(256)
void k_scatter1(const int* __restrict__ src, const int* __restrict__ dst,
                const float* __restrict__ m, float* __restrict__ y, int E) {
    int t = blockIdx.x * blockDim.x + threadIdx.x;
    int i = t * 8;
    if (i + 8 <= E) {
        vint4 s0 = __builtin_nontemporal_load((const vint4*)(src + i));
        vint4 s1 = __builtin_nontemporal_load((const vint4*)(src + i + 4));
        vint4 d0 = __builtin_nontemporal_load((const vint4*)(dst + i));
        vint4 d1 = __builtin_nontemporal_load((const vint4*)(dst + i + 4));
        unsafeAtomicAdd(&y[d0.x], m[s0.x]);
        unsafeAtomicAdd(&y[d0.y], m[s0.y]);
        unsafeAtomicAdd(&y[d0.z], m[s0.z]);
        unsafeAtomicAdd(&y[d0.w], m[s0.w]);
        unsafeAtomicAdd(&y[d1.x], m[s1.x]);
        unsafeAtomicAdd(&y[d1.y], m[s1.y]);
        unsafeAtomicAdd(&y[d1.z], m[s1.z]);
        unsafeAtomicAdd(&y[d1.w], m[s1.w]);
    } else if (i < E) {
        for (int j = i; j < E; ++j)
            unsafeAtomicAdd(&y[dst[j]], m[src[j]]);
    }
}

__global__ __launch_bounds__(256)
void k_classify(const float* __restrict__ y, unsigned char* __restrict__ cls, int N) {
    int i = blockIdx.x * blockDim.x + threadIdx.x;
    if (i < N) {
        float v = y[i];
        cls[i] = (v > 0.0f) ? 1 : ((v < 0.0f) ? 2 : 0);
    }
}

__global__ __launch_bounds__(256)
void k_scatter2(const int* __restrict__ src, const int* __restrict__ dst,
                const unsigned char* __restrict__ cls, unsigned int* __restrict__ pk,
                int E) {
    int t = blockIdx.x * blockDim.x + threadIdx.x;
    int i = t * 8;
    auto dec = [](unsigned char c) -> unsigned int {
        return (c == 1) ? 65536u : ((c == 2) ? 1u : 0u);
    };
    if (i + 8 <= E) {
        vint4 s0 = __builtin_nontemporal_load((const vint4*)(src + i));
        vint4 s1 = __builtin_nontemporal_load((const vint4*)(src + i + 4));
        vint4 d0 = __builtin_nontemporal_load((const vint4*)(dst + i));
        vint4 d1 = __builtin_nontemporal_load((const vint4*)(dst + i + 4));
        atomicAdd(&pk[d0.x], dec(cls[s0.x]));
        atomicAdd(&pk[d0.y], dec(cls[s0.y]));
        atomicAdd(&pk[d0.z], dec(cls[s0.z]));
        atomicAdd(&pk[d0.w], dec(cls[s0.w]));
        atomicAdd(&pk[d1.x], dec(cls[s1.x]));
        atomicAdd(&pk[d1.y], dec(cls[s1.y]));
        atomicAdd(&pk[d1.z], dec(cls[s1.z]));
        atomicAdd(&pk[d1.w], dec(cls[s1.w]));
    } else if (i < E) {
        for (int j = i; j < E; ++j)
            atomicAdd(&pk[dst[j]], dec(cls[src[j]]));
    }
}

__global__ __launch_bounds__(256)
void k_final(const unsigned int* __restrict__ pk, const float* __restrict__ W,
             const float* __restrict__ fw, float* __restrict__ out, int N) {
    int i = blockIdx.x * blockDim.x + threadIdx.x;
    if (i < N) {
        unsigned p = pk[i];
        float c0 = (float)(p >> 16);
        float c1 = (float)(p & 0xFFFFu);
        float x0 = fmaxf(c0 * W[0] + c1 * W[2], 0.0f);
        float x1 = fmaxf(c0 * W[1] + c1 * W[3], 0.0f);
        float z = x0 * fw[0] + x1 * fw[1];
        out[i] = 1.0f / (1.0f + expf(-z));
    }
}

// ===================== launch =====================

extern "C" void kernel_launch(void* const* d_in, const int* in_sizes, int n_in,
                              void* d_out, int out_size, void* d_ws, size_t ws_size,
                              hipStream_t stream) {
    const float* x  = (const float*)d_in[0];
    const int*   ei = (const int*)d_in[1];
    const float* W  = (const float*)d_in[2];
    const float* fw = (const float*)d_in[3];
    float*       out = (float*)d_out;

    const int N = in_sizes[0] / 2;
    const int E = in_sizes[1] / 2;
    const int* src = ei;
    const int* dst = ei + E;

    const int B  = 256;
    const int gN = (N + B - 1) / B;

    // sort-path sizing: 256 bins of 4096 nodes
    const int NB = (N + BNODES - 1) / BNODES;
    double mean = (double)E / ((double)N / (double)BNODES);
    unsigned CAP = (unsigned)(mean + 8.0 * sqrt(mean) + 1024.0);
    CAP = (CAP + 1023u) & ~1023u;

    const int NW = (N + 15) >> 4;   // packed class words
    const int n2 = NB * NB2;        // second-level count table entries

    char* p = (char*)d_ws;
    float*         m_s   = (float*)p;          p += (((size_t)N * 4 + 255) & ~255ULL);
    unsigned int*  gcur  = (unsigned int*)p;   p += (((size_t)NB * 4 + 255) & ~255ULL);
    float*         y_s   = (float*)p;          p += (((size_t)N * 4 + 255) & ~255ULL);
    unsigned int*  cls2  = (unsigned int*)p;   p += (((size_t)NW * 4 + 255) & ~255ULL);
    unsigned int*  cnt2    = (unsigned int*)p; p += (((size_t)n2 * 4 + 255) & ~255ULL);
    unsigned int*  gstart2 = (unsigned int*)p; p += (((size_t)n2 * 4 + 255) & ~255ULL);
    unsigned int*  gcur2   = (unsigned int*)p; p += (((size_t)n2 * 4 + 255) & ~255ULL);
    unsigned int*  gsorted = (unsigned int*)p;
    size_t sorted_bytes = (size_t)NB * CAP * 4ULL;
    unsigned int*  gsorted2 = (unsigned int*)(p + ((sorted_bytes + 255) & ~255ULL));
    size_t fixed = (size_t)(p - (char*)d_ws);
    size_t need_t2 = fixed + sorted_bytes;
    size_t need_t1 = fixed + ((sorted_bytes + 255) & ~255ULL) + sorted_bytes;

    if (ws_size >= need_t2 && N <= (1 << 20) && NB <= NBINS) {
        const bool tier1 = (ws_size >= need_t1);
        const int gP = (E + CHUNK - 1) / CHUNK;
        unsigned int* pk_s = (unsigned int*)y_s;   // pk aliases y (see k_classify2)
        k_prep2<<<gN, B, 0, stream>>>((const float2*)x, W, m_s, y_s, gcur,
                                      tier1 ? cnt2 : nullptr, N, NB, CAP, n2);
        k_permute<<<gP, PTHREADS, 0, stream>>>(src, dst, gsorted, gcur, E);
        if (tier1) {
            const int HS = (int)((CAP + H2CHUNK - 1) / H2CHUNK);
            const int PS = (int)((CAP + P2CHUNK - 1) / P2CHUNK);
            k_hist2<<<dim3(NB, HS), 256, 0, stream>>>(gsorted, gcur, cnt2, CAP);
            k_scan2<<<NB, NB2, 0, stream>>>(cnt2, gstart2, gcur2, CAP);
            k_permute2<<<dim3(NB, PS), PTHREADS, 0, stream>>>(gsorted, gcur, gsorted2, gcur2, CAP);
            k_agg1t<<<dim3(NB, SPLITS), 1024, 0, stream>>>(gsorted2, gstart2, gcur2, m_s, y_s, N);
            k_classify2<<<(NW + B - 1) / B, B, 0, stream>>>(y_s, cls2, pk_s, N);
            k_agg2t<<<dim3(NB, SPLITS), 1024, 0, stream>>>(gsorted2, gstart2, gcur2, cls2, pk_s, N);
        } else {
            k_agg1g<<<NB * SPLITS, 1024, 0, stream>>>(gsorted, gcur, m_s, y_s, N, CAP, NB);
            k_classify2<<<(NW + B - 1) / B, B, 0, stream>>>(y_s, cls2, pk_s, N);
            k_agg2s<<<NB * SPLITS, 1024, 0, stream>>>(gsorted, gcur, cls2, pk_s, N, CAP, NB);
        }
        k_final<<<gN, B, 0, stream>>>(pk_s, W, fw, out, N);
    } else {
        // fallback: R3 atomic path
        char* q = (char*)d_ws;
        unsigned char* cls = (unsigned char*)q;  q += (((size_t)N + 255) & ~255ULL);
        float*         m   = (float*)q;          q += (((size_t)N * 4 + 255) & ~255ULL);
        float*         y   = (float*)q;          q += (((size_t)N * 4 + 255) & ~255ULL);
        unsigned int*  pk  = (unsigned int*)q;
        const int gE = (E / 8 + B - 1) / B + 1;
        k_prep<<<gN, B, 0, stream>>>((const float2*)x, W, m, y, pk, N);
        k_scatter1<<<gE, B, 0, stream>>>(src, dst, m, y, E);
        k_classify<<<gN, B, 0, stream>>>(y, cls, N);
        k_scatter2<<<gE, B, 0, stream>>>(src, dst, cls, pk, E);
        k_final<<<gN, B, 0, stream>>>(pk, W, fw, out, N);
    }
}